// Round 4
// baseline (8832.063 us; speedup 1.0000x reference)
//
#include <hip/hip_runtime.h>
#include <stdint.h>

#define NBATCH 128
#define NNEUR  4096
#define TLAST  180                      // outputs depend only on steps 0..180
#define DECAY  0.6065306597126334f      // float(exp(-0.5))
#define SCOPE  __HIP_MEMORY_SCOPE_AGENT

// Zero the per-batch barrier state each call (ws is poisoned / left dirty).
__global__ void lif_init(unsigned* cnt, unsigned* flag) {
    const int i = threadIdx.x;
    if (i < NBATCH) { cnt[i] = 0u; flag[i] = 0u; }
}

// ONE persistent kernel runs all 181 steps.
// Grid: 512 blocks = 128 batches x 4 column tiles (1024 cols each); 2 blocks/CU
// guaranteed resident via __launch_bounds__(256,2) -> no deadlock.
// Per step, the only cross-block dependency is batch b's spike bitmask (64 u64
// words, produced by b's 4 blocks) -> per-batch 4-way barrier with device-scope
// atomics; batches pipeline independently (no global convoy).
// volts / rec / window sums live in REGISTERS for the entire simulation.
__global__ __launch_bounds__(256, 2) void lif_persist(
    const float* __restrict__ ff, const float* __restrict__ W,
    const float* __restrict__ rec0, float* __restrict__ out,
    unsigned long long* __restrict__ bits,   // 2 x [128][64] u64, double-buffered
    unsigned* __restrict__ cnt, unsigned* __restrict__ flag)
{
#pragma clang fp contract(off)          // match numpy's separate mul/add roundings
    __shared__ unsigned short slist[NNEUR];
    __shared__ int scnt;

    const int tid  = threadIdx.x;
    const int lane = tid & 63;
    const int wid  = tid >> 6;
    const int bid  = blockIdx.x;
    const int b    = bid >> 2;                        // batch
    const int tile = bid & 3;
    const int c0   = (tile << 10) + (wid << 8);       // wave's 256-col base
    const int n0   = c0 + (lane << 2);                // lane's 4 columns

    const float* wbase = W + n0;
    const float* fptr  = ff + (((size_t)b * 200) << 12) + n0;
    const size_t idx   = ((size_t)b << 12) + (size_t)n0;

    float4 v4 = make_float4(0.f, 0.f, 0.f, 0.f);      // volts
    float4 r4 = *(const float4*)(rec0 + idx);         // rec
    float4 ss = v4, sv = v4;                          // window sums
    unsigned tgt = 0;                                 // completed barriers

    for (int t = 0; t <= TLAST; ++t) {
        const float4 f4 = *(const float4*)fptr;       // ff prefetch (independent)
        fptr += NNEUR;

        float4 acc = make_float4(0.f, 0.f, 0.f, 0.f);
        if (t > 0) {
            // ---- decode batch's spike bitmask into LDS index list (wave 0) ----
            const unsigned long long* bsrc =
                bits + (((size_t)((t - 1) & 1)) << 13) + (b << 6);
            if (wid == 0) {
                unsigned long long m =
                    __hip_atomic_load(&bsrc[lane], __ATOMIC_RELAXED, SCOPE);
                const int c = __popcll(m);
                int x = c;
                #pragma unroll
                for (int o = 1; o < 64; o <<= 1) {
                    int y = __shfl_up(x, (unsigned)o);
                    if (lane >= o) x += y;
                }
                if (lane == 63) scnt = x;
                int widx = x - c;                               // exclusive prefix
                const int jb = ((lane >> 2) << 8) + (lane & 3); // word's col base
                while (m) {
                    const int u = __builtin_ctzll(m);
                    m &= m - 1;
                    slist[widx++] = (unsigned short)(jb + (u << 2));
                }
            }
            __syncthreads();

            // ---- sparse gather: hidden slice = sum of spiking rows of W ----
            const int cn = scnt;
            #pragma unroll 4
            for (int i = 0; i < cn; ++i) {
                const int j = slist[i];                         // uniform per wave
                const float4 wv = *(const float4*)(wbase + ((size_t)j << 12));
                acc.x += wv.x; acc.y += wv.y; acc.z += wv.z; acc.w += wv.w;
            }
        }

        // ---- elementwise LIF update (exact numpy op order) ----
        r4.x = r4.x * DECAY + acc.x * 0.5f;
        r4.y = r4.y * DECAY + acc.y * 0.5f;
        r4.z = r4.z * DECAY + acc.z * 0.5f;
        r4.w = r4.w * DECAY + acc.w * 0.5f;

        v4.x = v4.x * DECAY + 0.5f * (f4.x + r4.x);
        v4.y = v4.y * DECAY + 0.5f * (f4.y + r4.y);
        v4.z = v4.z * DECAY + 0.5f * (f4.z + r4.z);
        v4.w = v4.w * DECAY + 0.5f * (f4.w + r4.w);

        const bool s0 = v4.x >= 1.0f, s1 = v4.y >= 1.0f,
                   s2 = v4.z >= 1.0f, s3 = v4.w >= 1.0f;
        if (s0) v4.x = 0.f;
        if (s1) v4.y = 0.f;
        if (s2) v4.z = 0.f;
        if (s3) v4.w = 0.f;

        // ---- publish new spike bitmask (agent-scope so all XCDs see it) ----
        const unsigned long long m0 = __ballot(s0), m1 = __ballot(s1),
                                 m2 = __ballot(s2), m3 = __ballot(s3);
        if (t < TLAST && lane == 0) {
            unsigned long long* dst =
                bits + (((size_t)(t & 1)) << 13) + (b << 6) + (c0 >> 6);
            __hip_atomic_store(&dst[0], m0, __ATOMIC_RELAXED, SCOPE);
            __hip_atomic_store(&dst[1], m1, __ATOMIC_RELAXED, SCOPE);
            __hip_atomic_store(&dst[2], m2, __ATOMIC_RELAXED, SCOPE);
            __hip_atomic_store(&dst[3], m3, __ATOMIC_RELAXED, SCOPE);
        }

        // ---- recording windows (sums in registers) ----
        if (t >= 80) {
            const float4 s4 = make_float4(s0 ? 1.f : 0.f, s1 ? 1.f : 0.f,
                                          s2 ? 1.f : 0.f, s3 ? 1.f : 0.f);
            const bool start = (t == 80) || (t == 101) || (t == 121) ||
                               (t == 141) || (t == 161);
            if (start) {
                ss = s4; sv = v4;
            } else {
                ss.x += s4.x; ss.y += s4.y; ss.z += s4.z; ss.w += s4.w;
                sv.x += v4.x; sv.y += v4.y; sv.z += v4.z; sv.w += v4.w;
            }
            if (t == 100 || t == 120 || t == 140 || t == 160 || t == 180) {
                const int k = (t - 100) / 20;
                const size_t oidx = (((size_t)b * 5 + (size_t)k) << 12) + n0;
                float* rates = out;
                float* vavg  = out + (size_t)NBATCH * 5 * NNEUR;
                float* srec  = out + (size_t)NBATCH * 5 * NNEUR * 2;
                *(float4*)(rates + oidx) = make_float4(ss.x / 20.f, ss.y / 20.f,
                                                       ss.z / 20.f, ss.w / 20.f);
                *(float4*)(vavg + oidx)  = make_float4(sv.x / 20.f, sv.y / 20.f,
                                                       sv.z / 20.f, sv.w / 20.f);
                *(float4*)(srec + oidx)  = s4;
            }
        }

        // ---- per-batch barrier: 4 blocks of batch b rendezvous ----
        if (t < TLAST) {
            ++tgt;
            if (tid == 0) {
                const unsigned pos =
                    __hip_atomic_fetch_add(&cnt[b], 1u, __ATOMIC_ACQ_REL, SCOPE);
                if (pos == 3u) {
                    __hip_atomic_store(&cnt[b], 0u, __ATOMIC_RELAXED, SCOPE);
                    __hip_atomic_fetch_add(&flag[b], 1u, __ATOMIC_RELEASE, SCOPE);
                } else {
                    while (__hip_atomic_load(&flag[b], __ATOMIC_ACQUIRE, SCOPE) < tgt) {}
                }
            }
            __syncthreads();   // releases block; also guards slist reuse
        }
    }
}

extern "C" void kernel_launch(void* const* d_in, const int* in_sizes, int n_in,
                              void* d_out, int out_size, void* d_ws, size_t ws_size,
                              hipStream_t stream) {
    const float* ff   = (const float*)d_in[0];   // [128][200][4096] f32
    const float* W    = (const float*)d_in[1];   // [4096][4096] f32 (Wab_T)
    const float* rec0 = (const float*)d_in[2];   // [128][4096] f32
    float* out = (float*)d_out;                  // rates | volts_avg | spikes_rec

    char* ws = (char*)d_ws;
    unsigned long long* bits = (unsigned long long*)ws;            // 2*8192 u64 = 128 KB
    unsigned* cnt  = (unsigned*)(ws + 2 * 8192 * sizeof(unsigned long long));
    unsigned* flag = cnt + NBATCH;

    lif_init<<<dim3(1), dim3(128), 0, stream>>>(cnt, flag);
    lif_persist<<<dim3(512), dim3(256), 0, stream>>>(ff, W, rec0, out,
                                                     bits, cnt, flag);
}

// Round 5
// 6393.610 us; speedup vs baseline: 1.3814x; 1.3814x over previous
//
#include <hip/hip_runtime.h>
#include <stdint.h>

#define NBATCH 128
#define NNEUR  4096
#define TLAST  180                      // outputs depend only on steps 0..180
#define DECAY  0.6065306597126334f      // float(exp(-0.5))

// One kernel per time step.
// Grid: 1024 blocks = 128 batches x 8 column tiles (512 cols); bid = b*8 + tile
// puts ALL 128 batches of tile t on XCD t (bid % 8) -> row-slice L2 reuse.
// Block: 256 threads = 4 waves; wave w owns cols [tile*512 + w*128, +128), 2/lane.
// Gather is processed in 8 row-chunks of 512 so co-XCD blocks sweep W in rough
// lockstep: chunk working set (~1MB) stays L2-resident, followers hit L2.
// Chunking is a pure loop split: add order identical to the previous kernel.
__global__ __launch_bounds__(256) void lif_step(
    const float* __restrict__ ff, const float* __restrict__ W,
    const float* __restrict__ rec0, float* __restrict__ out,
    float* __restrict__ volts, float* __restrict__ rec,
    float* __restrict__ sum_s, float* __restrict__ sum_v,
    const unsigned long long* __restrict__ bits_old,
    unsigned long long* __restrict__ bits_new, int t)
{
#pragma clang fp contract(off)          // match numpy's separate mul/add roundings
    __shared__ __align__(16) unsigned short slist[NNEUR];
    __shared__ int cs[9];               // chunk start offsets; cs[8] = count

    const int tid  = threadIdx.x;
    const int lane = tid & 63;
    const int wid  = tid >> 6;
    const int bid  = blockIdx.x;
    const int b    = bid >> 3;                        // batch
    const int tile = bid & 7;
    const int c0   = (tile << 9) + (wid << 7);        // wave's 128-col base
    const int n0   = c0 + (lane << 1);                // lane's first col
    const unsigned laneb = (unsigned)n0 * 4u;         // byte offset within a W row

    // hoisted independent loads (ff + state) so they overlap the gather
    const size_t idx = ((size_t)b << 12) + (size_t)n0;
    const float2 f2  = *(const float2*)(ff + (((size_t)b * 200 + (size_t)t) << 12) + n0);

    float accx = 0.f, accy = 0.f;

    if (t > 0) {
        // ---- decode this batch's spike bitmask into an LDS index list (wave 0) ----
        // word `lane` covers cols [(lane>>1)*128, +128) of parity (lane&1);
        // row-chunk c (512 rows) == words [8c, 8c+8) -> chunk starts at lane 8c.
        if (wid == 0) {
            unsigned long long m = bits_old[(b << 6) + lane];   // word `lane`
            int c = __popcll(m);
            int x = c;
            #pragma unroll
            for (int o = 1; o < 64; o <<= 1) {
                int y = __shfl_up(x, (unsigned)o);
                if (lane >= o) x += y;
            }
            if (lane == 63) cs[8] = x;
            const int widx0 = x - c;                            // exclusive prefix
            if ((lane & 7) == 0) cs[lane >> 3] = widx0;
            int widx = widx0;
            const int jb = ((lane >> 1) << 7) + (lane & 1);     // col base of word
            while (m) {
                const int u = __builtin_ctzll(m);
                m &= m - 1;
                slist[widx++] = (unsigned short)(jb + (u << 1));
            }
        }
        __syncthreads();

        // ---- sparse gather in 8 row-chunks (phase-locked across co-XCD blocks) ----
        const char* Wb = (const char*)W;
        #pragma unroll
        for (int ch = 0; ch < 8; ++ch) {
            const int e = cs[ch + 1];
            #pragma unroll 4
            for (int i = cs[ch]; i < e; ++i) {
                const unsigned q =
                    __builtin_amdgcn_readfirstlane((unsigned)slist[i]);
                const float2 wv = *(const float2*)(Wb + ((q << 14) + laneb));
                accx += wv.x; accy += wv.y;
            }
        }
    }

    // ---- elementwise LIF update (exact numpy op order, no contraction) ----
    float2 r2 = (t == 0) ? *(const float2*)(rec0 + idx)
                         : *(const float2*)(rec + idx);
    r2.x = r2.x * DECAY + accx * 0.5f;
    r2.y = r2.y * DECAY + accy * 0.5f;

    float2 v2 = make_float2(0.f, 0.f);
    if (t > 0) v2 = *(const float2*)(volts + idx);
    v2.x = v2.x * DECAY + 0.5f * (f2.x + r2.x);
    v2.y = v2.y * DECAY + 0.5f * (f2.y + r2.y);

    const bool s0 = v2.x >= 1.0f, s1 = v2.y >= 1.0f;
    if (s0) v2.x = 0.f;
    if (s1) v2.y = 0.f;

    *(float2*)(volts + idx) = v2;
    *(float2*)(rec + idx)   = r2;

    // ---- new spike bitmask: raw ballots, 2 words per wave ----
    const unsigned long long m0 = __ballot(s0), m1 = __ballot(s1);
    if (lane == 0) {
        unsigned long long* dst = bits_new + (b << 6) + ((c0 >> 7) << 1);
        dst[0] = m0; dst[1] = m1;
    }

    // ---- recording windows: steps 80..100 -> k0, 101..120 -> k1, ... 161..180 -> k4 ----
    if (t >= 80) {
        const float2 s2 = make_float2(s0 ? 1.f : 0.f, s1 ? 1.f : 0.f);
        const bool start = (t == 80) || (t == 101) || (t == 121) || (t == 141) || (t == 161);
        float2 ss, sv;
        if (start) {
            ss = s2; sv = v2;
        } else {
            ss = *(const float2*)(sum_s + idx);
            sv = *(const float2*)(sum_v + idx);
            ss.x += s2.x; ss.y += s2.y;
            sv.x += v2.x; sv.y += v2.y;
        }
        *(float2*)(sum_s + idx) = ss;
        *(float2*)(sum_v + idx) = sv;

        if (t >= 100 && ((t - 100) % 20) == 0) {
            const int k = (t - 100) / 20;
            const size_t oidx = (((size_t)b * 5 + (size_t)k) << 12) + n0;
            float* rates = out;
            float* vavg  = out + (size_t)NBATCH * 5 * NNEUR;
            float* srec  = out + (size_t)NBATCH * 5 * NNEUR * 2;
            *(float2*)(rates + oidx) = make_float2(ss.x / 20.f, ss.y / 20.f);
            *(float2*)(vavg  + oidx) = make_float2(sv.x / 20.f, sv.y / 20.f);
            *(float2*)(srec  + oidx) = s2;
        }
    }
}

extern "C" void kernel_launch(void* const* d_in, const int* in_sizes, int n_in,
                              void* d_out, int out_size, void* d_ws, size_t ws_size,
                              hipStream_t stream) {
    const float* ff   = (const float*)d_in[0];   // [128][200][4096] f32
    const float* W    = (const float*)d_in[1];   // [4096][4096] f32 (Wab_T)
    const float* rec0 = (const float*)d_in[2];   // [128][4096] f32
    float* out = (float*)d_out;                  // rates | volts_avg | spikes_rec

    char* ws = (char*)d_ws;
    const size_t STATE = (size_t)NBATCH * NNEUR * sizeof(float);   // 2 MB
    float* volts = (float*)(ws);
    float* rec   = (float*)(ws + STATE);
    float* sum_s = (float*)(ws + 2 * STATE);
    float* sum_v = (float*)(ws + 3 * STATE);
    unsigned long long* bits = (unsigned long long*)(ws + 4 * STATE);
    const int BWORDS = NBATCH * (NNEUR / 64);    // 8192 words per buffer

    for (int t = 0; t <= TLAST; ++t) {
        lif_step<<<dim3(1024), dim3(256), 0, stream>>>(
            ff, W, rec0, out, volts, rec, sum_s, sum_v,
            bits + (size_t)(t & 1) * BWORDS,
            bits + (size_t)((t + 1) & 1) * BWORDS, t);
    }
}